// Round 10
// baseline (579.156 us; speedup 1.0000x reference)
//
#include <hip/hip_runtime.h>
#include <hip/hip_fp16.h>
#include <math.h>

// Problem constants (shapes follow the reference; N and E derived from in_sizes)
#define DIMX   256
#define HEADS  16
#define QKD    8
#define DH     128           // HEADS*QKD
#define QKVW   512           // 2*DH + DIMX
#define KVW    384           // fp16 row: k(128) | v(256)
#define INRPE  18
#define SCALE  0.35355339059327373f   // 8^-0.5

typedef __attribute__((ext_vector_type(8))) short bf16x8;
typedef __attribute__((ext_vector_type(4))) float f32x4;

// ---------------------------------------------------------------------------
// fp32 -> bf16 hi/lo split (RTN). hi + lo reproduces x to ~2^-16 relative.
// ---------------------------------------------------------------------------
__device__ __forceinline__ void split1(float v, unsigned short& h, unsigned short& l)
{
    unsigned b  = __float_as_uint(v);
    unsigned hb = (b + 0x7FFFu + ((b >> 16) & 1u)) & 0xFFFF0000u;  // RTN-even
    h = (unsigned short)(hb >> 16);
    float r = v - __uint_as_float(hb);                              // exact
    unsigned rb = __float_as_uint(r);
    l = (unsigned short)((rb + 0x7FFFu + ((rb >> 16) & 1u)) >> 16);
}

// x (Nn x 256 fp32) -> xh, xl (Mpad x 256 bf16 as ushort); pad rows zeroed.
__global__ __launch_bounds__(256) void convert_x(
    const float* __restrict__ x, unsigned short* __restrict__ xh,
    unsigned short* __restrict__ xl, int Nn, int Mpad)
{
    size_t total = (size_t)Mpad * 64;   // float4 chunks (64 per row)
    for (size_t i = (size_t)blockIdx.x * blockDim.x + threadIdx.x; i < total;
         i += (size_t)gridDim.x * blockDim.x) {
        size_t row = i >> 6;
        float4 v = make_float4(0.f, 0.f, 0.f, 0.f);
        if (row < (size_t)Nn) v = *(const float4*)&x[i * 4];
        ushort4 h, l;
        split1(v.x, h.x, l.x);
        split1(v.y, h.y, l.y);
        split1(v.z, h.z, l.z);
        split1(v.w, h.w, l.w);
        *(ushort4*)&xh[i * 4] = h;
        *(ushort4*)&xl[i * 4] = l;
    }
}

// W (256 x 512 fp32) -> Wt hi/lo (512 x 256 bf16), transposed for frag loads.
__global__ __launch_bounds__(256) void convert_w(
    const float* __restrict__ W, unsigned short* __restrict__ wth,
    unsigned short* __restrict__ wtl)
{
    int n = blockIdx.x;      // 512
    int k = threadIdx.x;     // 256
    float v = W[(size_t)k * QKVW + n];
    unsigned short h, l;
    split1(v, h, l);
    wth[(size_t)n * DIMX + k] = h;
    wtl[(size_t)n * DIMX + k] = l;
}

// ---------------------------------------------------------------------------
// Kernel 1 (MFMA): x @ Wqkv + b via 3xBF16 split (hi*hi + hi*lo + lo*hi).
// Outputs: q*SCALE -> qbuf (fp32, Nn x 128); k,v -> kvb (fp16, Nn x 384 row =
// [k(128)|v(256)]). No LDS, no barriers. 256 thr = 4 waves (2x2), 128x128
// tile, 4x4 frags of 16x16, K-steps of 32.
// GRID IS (4, Mblocks): col-panel in x (fastest) so the 4 col-blocks sharing
// the same 128 x-rows are dispatch-adjacent -> A hi/lo streams read from HBM
// once, then L2.
// ---------------------------------------------------------------------------
__global__ __launch_bounds__(256, 3) void qkv_gemm_mfma(
    const unsigned short* __restrict__ xh, const unsigned short* __restrict__ xl,
    const unsigned short* __restrict__ wth, const unsigned short* __restrict__ wtl,
    const float* __restrict__ bias, float* __restrict__ qbuf,
    __half* __restrict__ kvb, int Nn)
{
    int tid  = threadIdx.x;
    int w    = tid >> 6, lane = tid & 63;
    int wm   = w >> 1,   wn   = w & 1;
    int row0 = blockIdx.y * 128 + wm * 64;
    int col0 = blockIdx.x * 128 + wn * 64;
    int lrow = lane & 15;
    int lk8  = (lane >> 4) * 8;

    const unsigned short* pah = xh  + (size_t)(row0 + lrow) * DIMX + lk8;
    const unsigned short* pal = xl  + (size_t)(row0 + lrow) * DIMX + lk8;
    const unsigned short* pbh = wth + (size_t)(col0 + lrow) * DIMX + lk8;
    const unsigned short* pbl = wtl + (size_t)(col0 + lrow) * DIMX + lk8;

    f32x4 acc[4][4];
    #pragma unroll
    for (int i = 0; i < 4; i++)
        #pragma unroll
        for (int j = 0; j < 4; j++)
            acc[i][j] = (f32x4){0.f, 0.f, 0.f, 0.f};

    for (int t = 0; t < DIMX / 32; ++t) {
        int kb = t * 32;
        bf16x8 ah[4], al[4], bh[4], bl[4];
        #pragma unroll
        for (int f = 0; f < 4; ++f) {
            ah[f] = *(const bf16x8*)(pah + (size_t)f * 4096 + kb);
            al[f] = *(const bf16x8*)(pal + (size_t)f * 4096 + kb);
            bh[f] = *(const bf16x8*)(pbh + (size_t)f * 4096 + kb);
            bl[f] = *(const bf16x8*)(pbl + (size_t)f * 4096 + kb);
        }
        #pragma unroll
        for (int fm = 0; fm < 4; ++fm)
            #pragma unroll
            for (int fn = 0; fn < 4; ++fn) {
                acc[fm][fn] = __builtin_amdgcn_mfma_f32_16x16x32_bf16(
                    ah[fm], bh[fn], acc[fm][fn], 0, 0, 0);
                acc[fm][fn] = __builtin_amdgcn_mfma_f32_16x16x32_bf16(
                    ah[fm], bl[fn], acc[fm][fn], 0, 0, 0);
                acc[fm][fn] = __builtin_amdgcn_mfma_f32_16x16x32_bf16(
                    al[fm], bh[fn], acc[fm][fn], 0, 0, 0);
            }
    }

    int rbase = (lane >> 4) * 4;
    if (blockIdx.x == 0) {
        // q -> fp32 qbuf (row stride 128), pre-scaled
        #pragma unroll
        for (int fn = 0; fn < 4; ++fn) {
            float bv = bias[col0 + fn * 16 + lrow];
            #pragma unroll
            for (int fm = 0; fm < 4; ++fm)
                #pragma unroll
                for (int j = 0; j < 4; ++j) {
                    int r = row0 + fm * 16 + rbase + j;
                    if (r < Nn)
                        qbuf[(size_t)r * DH + col0 + fn * 16 + lrow] =
                            (acc[fm][fn][j] + bv) * SCALE;
                }
        }
    } else {
        // k (x==1) / v (x==2,3) -> fp16 kvb row [k(128)|v(256)]; base = col-128
        int base = col0 - 128;
        #pragma unroll
        for (int fn = 0; fn < 4; ++fn) {
            float bv = bias[col0 + fn * 16 + lrow];
            #pragma unroll
            for (int fm = 0; fm < 4; ++fm)
                #pragma unroll
                for (int j = 0; j < 4; ++j) {
                    int r = row0 + fm * 16 + rbase + j;
                    if (r < Nn)
                        kvb[(size_t)r * KVW + base + fn * 16 + lrow] =
                            __float2half(acc[fm][fn][j] + bv);
                }
        }
    }
}

// ---------------------------------------------------------------------------
// Kernel 1 fallback (fp32 vector ALU): used only if workspace too small.
// Same output layout as the MFMA path.
// ---------------------------------------------------------------------------
__global__ __launch_bounds__(256) void qkv_gemm(
    const float* __restrict__ x, const float* __restrict__ W,
    const float* __restrict__ bias, float* __restrict__ qbuf,
    __half* __restrict__ kvb, int Nn)
{
    __shared__ float As[16][132];
    __shared__ float Bs[16][132];

    int tid  = threadIdx.x;
    int row0 = blockIdx.x * 128;
    int col0 = blockIdx.y * 128;
    int tx = tid & 15, ty = tid >> 4;

    float acc[8][8] = {};

    for (int k0 = 0; k0 < DIMX; k0 += 16) {
        #pragma unroll
        for (int r = 0; r < 2; r++) {
            int idx  = tid + r * 256;
            int arow = idx >> 2, acol = (idx & 3) * 4;
            float4 av = make_float4(0.f, 0.f, 0.f, 0.f);
            int grow = row0 + arow;
            if (grow < Nn) av = *(const float4*)&x[(size_t)grow * DIMX + k0 + acol];
            As[acol + 0][arow] = av.x;
            As[acol + 1][arow] = av.y;
            As[acol + 2][arow] = av.z;
            As[acol + 3][arow] = av.w;
        }
        #pragma unroll
        for (int r = 0; r < 2; r++) {
            int idx  = tid + r * 256;
            int brow = idx >> 5, bcol = (idx & 31) * 4;
            float4 bv = *(const float4*)&W[(size_t)(k0 + brow) * QKVW + col0 + bcol];
            *(float4*)&Bs[brow][bcol] = bv;
        }
        __syncthreads();
        #pragma unroll
        for (int kk = 0; kk < 16; kk++) {
            float a0[8], b0[8];
            *(float4*)&a0[0] = *(const float4*)&As[kk][ty * 8];
            *(float4*)&a0[4] = *(const float4*)&As[kk][ty * 8 + 4];
            *(float4*)&b0[0] = *(const float4*)&Bs[kk][tx * 4];
            *(float4*)&b0[4] = *(const float4*)&Bs[kk][64 + tx * 4];
            #pragma unroll
            for (int i = 0; i < 8; i++)
                #pragma unroll
                for (int j = 0; j < 8; j++)
                    acc[i][j] = fmaf(a0[i], b0[j], acc[i][j]);
        }
        __syncthreads();
    }

    float4 bv0 = *(const float4*)&bias[col0 + tx * 4];
    float4 bv1 = *(const float4*)&bias[col0 + 64 + tx * 4];
    #pragma unroll
    for (int i = 0; i < 8; i++) {
        int grow = row0 + ty * 8 + i;
        if (grow < Nn) {
            float o0[4], o1[4];
            o0[0] = acc[i][0] + bv0.x; o0[1] = acc[i][1] + bv0.y;
            o0[2] = acc[i][2] + bv0.z; o0[3] = acc[i][3] + bv0.w;
            o1[0] = acc[i][4] + bv1.x; o1[1] = acc[i][5] + bv1.y;
            o1[2] = acc[i][6] + bv1.z; o1[3] = acc[i][7] + bv1.w;
            if (col0 == 0) {
                #pragma unroll
                for (int j = 0; j < 4; j++) {
                    qbuf[(size_t)grow * DH + tx * 4 + j]      = o0[j] * SCALE;
                    qbuf[(size_t)grow * DH + 64 + tx * 4 + j] = o1[j] * SCALE;
                }
            } else {
                int base = col0 - 128;
                #pragma unroll
                for (int j = 0; j < 4; j++) {
                    kvb[(size_t)grow * KVW + base + tx * 4 + j]      = __float2half(o0[j]);
                    kvb[(size_t)grow * KVW + base + 64 + tx * 4 + j] = __float2half(o1[j]);
                }
            }
        }
    }
}

// ---------------------------------------------------------------------------
// CSR build: count -> hierarchical parallel scan -> scatter
// ---------------------------------------------------------------------------
__global__ void count_kernel(const int* __restrict__ ei, int* __restrict__ deg, int E)
{
    int e = blockIdx.x * blockDim.x + threadIdx.x;
    if (e < E) atomicAdd(&deg[ei[e]], 1);
}

__device__ __forceinline__ int4 load_deg4(const int* __restrict__ deg, int base, int n)
{
    int4 v = make_int4(0, 0, 0, 0);
    if (base + 3 < n) v = *(const int4*)&deg[base];
    else {
        if (base + 0 < n) v.x = deg[base + 0];
        if (base + 1 < n) v.y = deg[base + 1];
        if (base + 2 < n) v.z = deg[base + 2];
        if (base + 3 < n) v.w = deg[base + 3];
    }
    return v;
}

// chunk = 1024 ints per block (256 thr x int4)
__global__ __launch_bounds__(256) void scan_sums(
    const int* __restrict__ deg, int* __restrict__ psum, int n)
{
    int base = blockIdx.x * 1024 + threadIdx.x * 4;
    int4 v = load_deg4(deg, base, n);
    int s = v.x + v.y + v.z + v.w;
    #pragma unroll
    for (int d = 1; d < 64; d <<= 1) s += __shfl_xor(s, d, 64);
    __shared__ int ws[4];
    int lane = threadIdx.x & 63, w = threadIdx.x >> 6;
    if (lane == 0) ws[w] = s;
    __syncthreads();
    if (threadIdx.x == 0) psum[blockIdx.x] = ws[0] + ws[1] + ws[2] + ws[3];
}

// exclusive scan of psum[nchunk] -> pbase; writes off[n] = total
__global__ __launch_bounds__(64) void scan_base(
    const int* __restrict__ psum, int* __restrict__ pbase,
    int* __restrict__ off, int n, int nchunk)
{
    int t = threadIdx.x;   // single wave
    int carry = 0;
    for (int base = 0; base < nchunk; base += 64) {
        int v = (base + t < nchunk) ? psum[base + t] : 0;
        int incl = v;
        #pragma unroll
        for (int d = 1; d < 64; d <<= 1) {
            int u = __shfl_up(incl, d, 64);
            if (t >= d) incl += u;
        }
        if (base + t < nchunk) pbase[base + t] = carry + incl - v;
        carry += __shfl(incl, 63, 64);
    }
    if (t == 0) off[n] = carry;
}

// per-chunk rescan + pbase offset -> exclusive off[0..n)
__global__ __launch_bounds__(256) void scan_final(
    const int* __restrict__ deg, const int* __restrict__ pbase,
    int* __restrict__ off, int n)
{
    int base = blockIdx.x * 1024 + threadIdx.x * 4;
    int4 v = load_deg4(deg, base, n);
    int e1 = v.x, e2 = e1 + v.y, e3 = e2 + v.z, T = e3 + v.w;
    int lane = threadIdx.x & 63, w = threadIdx.x >> 6;
    int incl = T;
    #pragma unroll
    for (int d = 1; d < 64; d <<= 1) {
        int u = __shfl_up(incl, d, 64);
        if (lane >= d) incl += u;
    }
    int lexcl = incl - T;
    __shared__ int ws[4];
    if (lane == 63) ws[w] = incl;
    __syncthreads();
    int wexcl = 0;
    #pragma unroll
    for (int j = 0; j < 4; j++) if (j < w) wexcl += ws[j];
    int o0 = pbase[blockIdx.x] + wexcl + lexcl;
    if (base + 0 < n) off[base + 0] = o0;
    if (base + 1 < n) off[base + 1] = o0 + e1;
    if (base + 2 < n) off[base + 2] = o0 + e2;
    if (base + 3 < n) off[base + 3] = o0 + e3;
}

__global__ void scatter_kernel(const int* __restrict__ ei,
                               const int* __restrict__ off, int* __restrict__ cur,
                               int2* __restrict__ elist, int E)
{
    int e = blockIdx.x * blockDim.x + threadIdx.x;
    if (e < E) {
        int s = ei[e];
        int t = ei[E + e];
        int pos = atomicAdd(&cur[s], 1);
        elist[off[s] + pos] = make_int2(e, t);
    }
}

// ---------------------------------------------------------------------------
// Kernel 2: node-centric fused attention. One block (128 thr = 2 waves) per
// node; thread t: head h = t>>3, qk-dim = t, v-dims 2t, 2t+1.
// Round-9 analysis: VALU model (74 inst/edge/wave = 296 SIMD-cyc) matches
// measured 46% VALUBusy of the 679 SIMD-cyc/edge budget -> ~380 cyc/edge are
// gather-latency stalls with only 1 edge in flight per block. THIS ROUND:
// 2-deep pipeline for the random (elist,k,v) chain (doubles outstanding
// gathers; +~4 regs only). edge_attr stays 1-deep (round-8: doubling ea
// state -> VGPR 72, occupancy 33%, 2x slower; do not repeat).
// Weights pinned opaque (AGPR-resident on unified RF).
// No running max (|compat| < ~30; exp safe in fp32, identical after norm).
// ---------------------------------------------------------------------------
__global__ __launch_bounds__(128, 2) void node_attn(
    const float* __restrict__ qbuf, const __half* __restrict__ kv,
    const int2* __restrict__ elist, const int* __restrict__ off,
    const float* __restrict__ edge_attr,
    const float* __restrict__ Wq_rpe, const float* __restrict__ bq_rpe,
    const float* __restrict__ Wk_rpe, const float* __restrict__ bk_rpe,
    float* __restrict__ out, int Nn)
{
    int tid = threadIdx.x;
    int n = blockIdx.x;

    // resident RPE weight columns for this thread's qk dim (= tid)
    float wq[INRPE], wk[INRPE];
    #pragma unroll
    for (int j = 0; j < INRPE; j++) {
        wq[j] = Wq_rpe[j * DH + tid];
        wk[j] = Wk_rpe[j * DH + tid];
    }
    #pragma unroll
    for (int j = 0; j < INRPE; j++) {
        asm volatile("" : "+v"(wq[j]), "+v"(wk[j]));
    }

    float qs = qbuf[(size_t)n * DH + tid] + bq_rpe[tid];
    float bkv = bk_rpe[tid];

    int beg = off[n], end = off[n + 1];
    if (beg == end) {
        *(float2*)&out[(size_t)n * DIMX + 2 * tid] = make_float2(0.f, 0.f);
        return;
    }

    float lsum = 0.0f;
    float2 o = make_float2(0.f, 0.f);

    // ---- prologue: kv staged 2 deep (edges beg, beg+1); ea staged 1 deep ----
    int2 etA = elist[beg];                                   // edge i
    int2 etB = elist[(beg + 1 < end) ? beg + 1 : beg];       // edge i+1
    __half  kA = kv[(size_t)etA.y * KVW + tid];
    __half2 vA = *(const __half2*)&kv[(size_t)etA.y * KVW + DH + 2 * tid];
    __half  kB = kv[(size_t)etB.y * KVW + tid];
    __half2 vB = *(const __half2*)&kv[(size_t)etB.y * KVW + DH + 2 * tid];
    float eac[INRPE];
    {
        const float2* p = (const float2*)(edge_attr + (size_t)etA.x * INRPE);
        #pragma unroll
        for (int j = 0; j < 9; j++) { float2 v2 = p[j]; eac[2*j] = v2.x; eac[2*j+1] = v2.y; }
    }

    #pragma unroll 1
    for (int i = beg; i < end; i++) {
        // ---- issue kv gather for edge i+2 (2 ahead) ----
        int inx2 = (i + 2 < end) ? i + 2 : end - 1;
        int2 etC = elist[inx2];
        __half  kC = kv[(size_t)etC.y * KVW + tid];
        __half2 vC = *(const __half2*)&kv[(size_t)etC.y * KVW + DH + 2 * tid];

        // ---- issue ea load for edge i+1 (1 ahead) ----
        float ean[INRPE];
        {
            const float2* p = (const float2*)(edge_attr + (size_t)etB.x * INRPE);
            #pragma unroll
            for (int j = 0; j < 9; j++) { float2 v2 = p[j]; ean[2*j] = v2.x; ean[2*j+1] = v2.y; }
        }

        // ---- compute edge i (all operands resident) ----
        float qr = 0.f, kr = bkv;
        #pragma unroll
        for (int j = 0; j < INRPE; j++) {
            qr = fmaf(eac[j], wq[j], qr);
            kr = fmaf(eac[j], wk[j], kr);
        }

        float c2 = (qs + qr) * (__half2float(kA) + kr);
        c2 += __shfl_xor(c2, 1, 64);
        c2 += __shfl_xor(c2, 2, 64);
        c2 += __shfl_xor(c2, 4, 64);

        float ex = __expf(c2);
        float2 vf = __half22float2(vA);
        lsum += ex;
        o.x = fmaf(ex, vf.x, o.x);
        o.y = fmaf(ex, vf.y, o.y);

        // ---- rotate pipeline ----
        kA = kB; vA = vB;
        kB = kC; vB = vC;
        etB = etC;
        #pragma unroll
        for (int j = 0; j < INRPE; j++) eac[j] = ean[j];
    }

    float inv = 1.0f / (lsum + 1e-16f);
    *(float2*)&out[(size_t)n * DIMX + 2 * tid] = make_float2(o.x * inv, o.y * inv);
}

// ---------------------------------------------------------------------------
extern "C" void kernel_launch(void* const* d_in, const int* in_sizes, int n_in,
                              void* d_out, int out_size, void* d_ws, size_t ws_size,
                              hipStream_t stream)
{
    const float* x    = (const float*)d_in[0];
    const int*   ei   = (const int*)d_in[1];     // int32! harness converts int64 -> int
    const float* ea   = (const float*)d_in[2];
    const float* Wqkv = (const float*)d_in[3];
    const float* bqkv = (const float*)d_in[4];
    const float* Wk   = (const float*)d_in[5];
    const float* bk   = (const float*)d_in[6];
    const float* Wq   = (const float*)d_in[7];
    const float* bq   = (const float*)d_in[8];

    int Nn = in_sizes[0] / DIMX;
    int E  = in_sizes[1] / 2;
    float* out = (float*)d_out;

    int Mblocks = (Nn + 127) / 128;
    int Mpad    = Mblocks * 128;
    int nchunk  = (Nn + 1023) / 1024;

    // workspace layout:
    //   [ qbuf : Nn*128 f32 ][ kvb : Nn*384 fp16 ]
    //   [ region P: gemm phase = xh/xl (Mpad*256 bf16 each) + wth/wtl
    //               csr  phase = deg/cur/off/elist/psum/pbase (aliased) ]
    size_t qb_bytes = (size_t)Nn * DH * sizeof(float);
    size_t kv_bytes = (size_t)Nn * KVW * sizeof(__half);
    float*  qbuf = (float*)d_ws;
    __half* kvb  = (__half*)((char*)d_ws + qb_bytes);
    char*   P    = (char*)d_ws + qb_bytes + kv_bytes;

    size_t xpart  = (size_t)Mpad * DIMX * sizeof(unsigned short);
    size_t wpart  = (size_t)QKVW * DIMX * sizeof(unsigned short);
    size_t gemm_bytes = 2 * xpart + 2 * wpart;
    size_t csr_bytes  = sizeof(int) * (size_t)(3 * Nn + 2 + 2 * nchunk + 8)
                      + sizeof(int2) * (size_t)E;
    size_t need = qb_bytes + kv_bytes
                + (gemm_bytes > csr_bytes ? gemm_bytes : csr_bytes);

    // CSR aliases (used strictly after the gemm has consumed xh/xl)
    int*  deg = (int*)P;
    int*  cur = deg + Nn;
    int*  off = cur + Nn;
    int2* elist = (int2*)(off + ((Nn + 2) & ~1));
    int*  psum  = (int*)(elist + E);
    int*  pbase = psum + nchunk;

    if (ws_size >= need) {
        unsigned short* xh  = (unsigned short*)P;
        unsigned short* xl  = xh + (size_t)Mpad * DIMX;
        unsigned short* wth = xl + (size_t)Mpad * DIMX;
        unsigned short* wtl = wth + (size_t)QKVW * DIMX;

        convert_x<<<2048, 256, 0, stream>>>(x, xh, xl, Nn, Mpad);
        convert_w<<<QKVW, 256, 0, stream>>>(Wqkv, wth, wtl);
        // grid (4, Mblocks): col-panels adjacent -> A rows fetched once
        qkv_gemm_mfma<<<dim3(4, Mblocks), 256, 0, stream>>>(xh, xl, wth, wtl,
                                                            bqkv, qbuf, kvb, Nn);
    } else {
        qkv_gemm<<<dim3(Mblocks, QKVW / 128), 256, 0, stream>>>(x, Wqkv, bqkv,
                                                                qbuf, kvb, Nn);
    }

    // CSR build AFTER gemm (deg/cur alias the bf16 staging region)
    hipMemsetAsync(deg, 0, sizeof(int) * 2 * (size_t)Nn, stream);
    count_kernel<<<(E + 255) / 256, 256, 0, stream>>>(ei, deg, E);
    scan_sums<<<nchunk, 256, 0, stream>>>(deg, psum, Nn);
    scan_base<<<1, 64, 0, stream>>>(psum, pbase, off, Nn, nchunk);
    scan_final<<<nchunk, 256, 0, stream>>>(deg, pbase, off, Nn);
    scatter_kernel<<<(E + 255) / 256, 256, 0, stream>>>(ei, off, cur, elist, E);

    node_attn<<<Nn, 128, 0, stream>>>(qbuf, kvb, elist, off, ea,
                                      Wq, bq, Wk, bk, out, Nn);
}

// Round 11
// 559.121 us; speedup vs baseline: 1.0358x; 1.0358x over previous
//
#include <hip/hip_runtime.h>
#include <hip/hip_fp16.h>
#include <math.h>

// Problem constants (shapes follow the reference; N and E derived from in_sizes)
#define DIMX   256
#define HEADS  16
#define QKD    8
#define DH     128           // HEADS*QKD
#define QKVW   512           // 2*DH + DIMX
#define KVW    384           // fp16 row: k(128) | v(256)
#define INRPE  18
#define SCALE  0.35355339059327373f   // 8^-0.5

typedef __attribute__((ext_vector_type(8))) short bf16x8;
typedef __attribute__((ext_vector_type(4))) float f32x4;

// ---------------------------------------------------------------------------
// fp32 -> bf16 hi/lo split (RTN). hi + lo reproduces x to ~2^-16 relative.
// ---------------------------------------------------------------------------
__device__ __forceinline__ void split1(float v, unsigned short& h, unsigned short& l)
{
    unsigned b  = __float_as_uint(v);
    unsigned hb = (b + 0x7FFFu + ((b >> 16) & 1u)) & 0xFFFF0000u;  // RTN-even
    h = (unsigned short)(hb >> 16);
    float r = v - __uint_as_float(hb);                              // exact
    unsigned rb = __float_as_uint(r);
    l = (unsigned short)((rb + 0x7FFFu + ((rb >> 16) & 1u)) >> 16);
}

// x (Nn x 256 fp32) -> xh, xl (Mpad x 256 bf16 as ushort); pad rows zeroed.
__global__ __launch_bounds__(256) void convert_x(
    const float* __restrict__ x, unsigned short* __restrict__ xh,
    unsigned short* __restrict__ xl, int Nn, int Mpad)
{
    size_t total = (size_t)Mpad * 64;   // float4 chunks (64 per row)
    for (size_t i = (size_t)blockIdx.x * blockDim.x + threadIdx.x; i < total;
         i += (size_t)gridDim.x * blockDim.x) {
        size_t row = i >> 6;
        float4 v = make_float4(0.f, 0.f, 0.f, 0.f);
        if (row < (size_t)Nn) v = *(const float4*)&x[i * 4];
        ushort4 h, l;
        split1(v.x, h.x, l.x);
        split1(v.y, h.y, l.y);
        split1(v.z, h.z, l.z);
        split1(v.w, h.w, l.w);
        *(ushort4*)&xh[i * 4] = h;
        *(ushort4*)&xl[i * 4] = l;
    }
}

// W (256 x 512 fp32) -> Wt hi/lo (512 x 256 bf16), transposed for frag loads.
__global__ __launch_bounds__(256) void convert_w(
    const float* __restrict__ W, unsigned short* __restrict__ wth,
    unsigned short* __restrict__ wtl)
{
    int n = blockIdx.x;      // 512
    int k = threadIdx.x;     // 256
    float v = W[(size_t)k * QKVW + n];
    unsigned short h, l;
    split1(v, h, l);
    wth[(size_t)n * DIMX + k] = h;
    wtl[(size_t)n * DIMX + k] = l;
}

// ---------------------------------------------------------------------------
// Kernel 1 (MFMA): x @ Wqkv + b via 3xBF16 split (hi*hi + hi*lo + lo*hi).
// Outputs: q*SCALE -> qbuf (fp32, Nn x 128); k,v -> kvb (fp16, Nn x 384 row =
// [k(128)|v(256)]). No LDS, no barriers. 256 thr = 4 waves (2x2), 128x128
// tile, 4x4 frags of 16x16, K-steps of 32.
// GRID IS (4, Mblocks): col-panel in x (fastest) so the 4 col-blocks sharing
// the same 128 x-rows are dispatch-adjacent -> A hi/lo streams read from HBM
// once, then L2.
// ---------------------------------------------------------------------------
__global__ __launch_bounds__(256, 3) void qkv_gemm_mfma(
    const unsigned short* __restrict__ xh, const unsigned short* __restrict__ xl,
    const unsigned short* __restrict__ wth, const unsigned short* __restrict__ wtl,
    const float* __restrict__ bias, float* __restrict__ qbuf,
    __half* __restrict__ kvb, int Nn)
{
    int tid  = threadIdx.x;
    int w    = tid >> 6, lane = tid & 63;
    int wm   = w >> 1,   wn   = w & 1;
    int row0 = blockIdx.y * 128 + wm * 64;
    int col0 = blockIdx.x * 128 + wn * 64;
    int lrow = lane & 15;
    int lk8  = (lane >> 4) * 8;

    const unsigned short* pah = xh  + (size_t)(row0 + lrow) * DIMX + lk8;
    const unsigned short* pal = xl  + (size_t)(row0 + lrow) * DIMX + lk8;
    const unsigned short* pbh = wth + (size_t)(col0 + lrow) * DIMX + lk8;
    const unsigned short* pbl = wtl + (size_t)(col0 + lrow) * DIMX + lk8;

    f32x4 acc[4][4];
    #pragma unroll
    for (int i = 0; i < 4; i++)
        #pragma unroll
        for (int j = 0; j < 4; j++)
            acc[i][j] = (f32x4){0.f, 0.f, 0.f, 0.f};

    for (int t = 0; t < DIMX / 32; ++t) {
        int kb = t * 32;
        bf16x8 ah[4], al[4], bh[4], bl[4];
        #pragma unroll
        for (int f = 0; f < 4; ++f) {
            ah[f] = *(const bf16x8*)(pah + (size_t)f * 4096 + kb);
            al[f] = *(const bf16x8*)(pal + (size_t)f * 4096 + kb);
            bh[f] = *(const bf16x8*)(pbh + (size_t)f * 4096 + kb);
            bl[f] = *(const bf16x8*)(pbl + (size_t)f * 4096 + kb);
        }
        #pragma unroll
        for (int fm = 0; fm < 4; ++fm)
            #pragma unroll
            for (int fn = 0; fn < 4; ++fn) {
                acc[fm][fn] = __builtin_amdgcn_mfma_f32_16x16x32_bf16(
                    ah[fm], bh[fn], acc[fm][fn], 0, 0, 0);
                acc[fm][fn] = __builtin_amdgcn_mfma_f32_16x16x32_bf16(
                    ah[fm], bl[fn], acc[fm][fn], 0, 0, 0);
                acc[fm][fn] = __builtin_amdgcn_mfma_f32_16x16x32_bf16(
                    al[fm], bh[fn], acc[fm][fn], 0, 0, 0);
            }
    }

    int rbase = (lane >> 4) * 4;
    if (blockIdx.x == 0) {
        // q -> fp32 qbuf (row stride 128), pre-scaled
        #pragma unroll
        for (int fn = 0; fn < 4; ++fn) {
            float bv = bias[col0 + fn * 16 + lrow];
            #pragma unroll
            for (int fm = 0; fm < 4; ++fm)
                #pragma unroll
                for (int j = 0; j < 4; ++j) {
                    int r = row0 + fm * 16 + rbase + j;
                    if (r < Nn)
                        qbuf[(size_t)r * DH + col0 + fn * 16 + lrow] =
                            (acc[fm][fn][j] + bv) * SCALE;
                }
        }
    } else {
        // k (x==1) / v (x==2,3) -> fp16 kvb row [k(128)|v(256)]; base = col-128
        int base = col0 - 128;
        #pragma unroll
        for (int fn = 0; fn < 4; ++fn) {
            float bv = bias[col0 + fn * 16 + lrow];
            #pragma unroll
            for (int fm = 0; fm < 4; ++fm)
                #pragma unroll
                for (int j = 0; j < 4; ++j) {
                    int r = row0 + fm * 16 + rbase + j;
                    if (r < Nn)
                        kvb[(size_t)r * KVW + base + fn * 16 + lrow] =
                            __float2half(acc[fm][fn][j] + bv);
                }
        }
    }
}

// ---------------------------------------------------------------------------
// Kernel 1 fallback (fp32 vector ALU): used only if workspace too small.
// Same output layout as the MFMA path.
// ---------------------------------------------------------------------------
__global__ __launch_bounds__(256) void qkv_gemm(
    const float* __restrict__ x, const float* __restrict__ W,
    const float* __restrict__ bias, float* __restrict__ qbuf,
    __half* __restrict__ kvb, int Nn)
{
    __shared__ float As[16][132];
    __shared__ float Bs[16][132];

    int tid  = threadIdx.x;
    int row0 = blockIdx.x * 128;
    int col0 = blockIdx.y * 128;
    int tx = tid & 15, ty = tid >> 4;

    float acc[8][8] = {};

    for (int k0 = 0; k0 < DIMX; k0 += 16) {
        #pragma unroll
        for (int r = 0; r < 2; r++) {
            int idx  = tid + r * 256;
            int arow = idx >> 2, acol = (idx & 3) * 4;
            float4 av = make_float4(0.f, 0.f, 0.f, 0.f);
            int grow = row0 + arow;
            if (grow < Nn) av = *(const float4*)&x[(size_t)grow * DIMX + k0 + acol];
            As[acol + 0][arow] = av.x;
            As[acol + 1][arow] = av.y;
            As[acol + 2][arow] = av.z;
            As[acol + 3][arow] = av.w;
        }
        #pragma unroll
        for (int r = 0; r < 2; r++) {
            int idx  = tid + r * 256;
            int brow = idx >> 5, bcol = (idx & 31) * 4;
            float4 bv = *(const float4*)&W[(size_t)(k0 + brow) * QKVW + col0 + bcol];
            *(float4*)&Bs[brow][bcol] = bv;
        }
        __syncthreads();
        #pragma unroll
        for (int kk = 0; kk < 16; kk++) {
            float a0[8], b0[8];
            *(float4*)&a0[0] = *(const float4*)&As[kk][ty * 8];
            *(float4*)&a0[4] = *(const float4*)&As[kk][ty * 8 + 4];
            *(float4*)&b0[0] = *(const float4*)&Bs[kk][tx * 4];
            *(float4*)&b0[4] = *(const float4*)&Bs[kk][64 + tx * 4];
            #pragma unroll
            for (int i = 0; i < 8; i++)
                #pragma unroll
                for (int j = 0; j < 8; j++)
                    acc[i][j] = fmaf(a0[i], b0[j], acc[i][j]);
        }
        __syncthreads();
    }

    float4 bv0 = *(const float4*)&bias[col0 + tx * 4];
    float4 bv1 = *(const float4*)&bias[col0 + 64 + tx * 4];
    #pragma unroll
    for (int i = 0; i < 8; i++) {
        int grow = row0 + ty * 8 + i;
        if (grow < Nn) {
            float o0[4], o1[4];
            o0[0] = acc[i][0] + bv0.x; o0[1] = acc[i][1] + bv0.y;
            o0[2] = acc[i][2] + bv0.z; o0[3] = acc[i][3] + bv0.w;
            o1[0] = acc[i][4] + bv1.x; o1[1] = acc[i][5] + bv1.y;
            o1[2] = acc[i][6] + bv1.z; o1[3] = acc[i][7] + bv1.w;
            if (col0 == 0) {
                #pragma unroll
                for (int j = 0; j < 4; j++) {
                    qbuf[(size_t)grow * DH + tx * 4 + j]      = o0[j] * SCALE;
                    qbuf[(size_t)grow * DH + 64 + tx * 4 + j] = o1[j] * SCALE;
                }
            } else {
                int base = col0 - 128;
                #pragma unroll
                for (int j = 0; j < 4; j++) {
                    kvb[(size_t)grow * KVW + base + tx * 4 + j]      = __float2half(o0[j]);
                    kvb[(size_t)grow * KVW + base + 64 + tx * 4 + j] = __float2half(o1[j]);
                }
            }
        }
    }
}

// ---------------------------------------------------------------------------
// CSR build: count -> hierarchical parallel scan -> scatter (+ea permute)
// ---------------------------------------------------------------------------
__global__ void count_kernel(const int* __restrict__ ei, int* __restrict__ deg, int E)
{
    int e = blockIdx.x * blockDim.x + threadIdx.x;
    if (e < E) atomicAdd(&deg[ei[e]], 1);
}

__device__ __forceinline__ int4 load_deg4(const int* __restrict__ deg, int base, int n)
{
    int4 v = make_int4(0, 0, 0, 0);
    if (base + 3 < n) v = *(const int4*)&deg[base];
    else {
        if (base + 0 < n) v.x = deg[base + 0];
        if (base + 1 < n) v.y = deg[base + 1];
        if (base + 2 < n) v.z = deg[base + 2];
        if (base + 3 < n) v.w = deg[base + 3];
    }
    return v;
}

// chunk = 1024 ints per block (256 thr x int4)
__global__ __launch_bounds__(256) void scan_sums(
    const int* __restrict__ deg, int* __restrict__ psum, int n)
{
    int base = blockIdx.x * 1024 + threadIdx.x * 4;
    int4 v = load_deg4(deg, base, n);
    int s = v.x + v.y + v.z + v.w;
    #pragma unroll
    for (int d = 1; d < 64; d <<= 1) s += __shfl_xor(s, d, 64);
    __shared__ int ws[4];
    int lane = threadIdx.x & 63, w = threadIdx.x >> 6;
    if (lane == 0) ws[w] = s;
    __syncthreads();
    if (threadIdx.x == 0) psum[blockIdx.x] = ws[0] + ws[1] + ws[2] + ws[3];
}

// exclusive scan of psum[nchunk] -> pbase; writes off[n] = total
__global__ __launch_bounds__(64) void scan_base(
    const int* __restrict__ psum, int* __restrict__ pbase,
    int* __restrict__ off, int n, int nchunk)
{
    int t = threadIdx.x;   // single wave
    int carry = 0;
    for (int base = 0; base < nchunk; base += 64) {
        int v = (base + t < nchunk) ? psum[base + t] : 0;
        int incl = v;
        #pragma unroll
        for (int d = 1; d < 64; d <<= 1) {
            int u = __shfl_up(incl, d, 64);
            if (t >= d) incl += u;
        }
        if (base + t < nchunk) pbase[base + t] = carry + incl - v;
        carry += __shfl(incl, 63, 64);
    }
    if (t == 0) off[n] = carry;
}

// per-chunk rescan + pbase offset -> exclusive off[0..n)
__global__ __launch_bounds__(256) void scan_final(
    const int* __restrict__ deg, const int* __restrict__ pbase,
    int* __restrict__ off, int n)
{
    int base = blockIdx.x * 1024 + threadIdx.x * 4;
    int4 v = load_deg4(deg, base, n);
    int e1 = v.x, e2 = e1 + v.y, e3 = e2 + v.z, T = e3 + v.w;
    int lane = threadIdx.x & 63, w = threadIdx.x >> 6;
    int incl = T;
    #pragma unroll
    for (int d = 1; d < 64; d <<= 1) {
        int u = __shfl_up(incl, d, 64);
        if (lane >= d) incl += u;
    }
    int lexcl = incl - T;
    __shared__ int ws[4];
    if (lane == 63) ws[w] = incl;
    __syncthreads();
    int wexcl = 0;
    #pragma unroll
    for (int j = 0; j < 4; j++) if (j < w) wexcl += ws[j];
    int o0 = pbase[blockIdx.x] + wexcl + lexcl;
    if (base + 0 < n) off[base + 0] = o0;
    if (base + 1 < n) off[base + 1] = o0 + e1;
    if (base + 2 < n) off[base + 2] = o0 + e2;
    if (base + 3 < n) off[base + 3] = o0 + e3;
}

// Scatter: target list + PERMUTED edge_attr. Reads ea coalesced (thread e
// reads row e), writes 72B to slot off[s]+pos. node_attn then reads ea
// sequentially with a UNIFORM index -> scalar (s_load) path, no per-edge
// indirection, and elist shrinks to int.
__global__ void scatter_kernel(const int* __restrict__ ei,
                               const float* __restrict__ ea,
                               const int* __restrict__ off, int* __restrict__ cur,
                               int* __restrict__ tlist, float* __restrict__ eaperm,
                               int E)
{
    int e = blockIdx.x * blockDim.x + threadIdx.x;
    if (e < E) {
        int s = ei[e];
        int t = ei[E + e];
        int pos = atomicAdd(&cur[s], 1);
        int idx = off[s] + pos;
        tlist[idx] = t;
        const float2* src = (const float2*)(ea + (size_t)e * INRPE);
        float2* dst = (float2*)(eaperm + (size_t)idx * INRPE);
        #pragma unroll
        for (int j = 0; j < 9; j++) dst[j] = src[j];
    }
}

// ---------------------------------------------------------------------------
// Kernel 2: node-centric fused attention. One block (128 thr = 2 waves) per
// node; thread t: head h = t>>3, qk-dim = t, v-dims 2t, 2t+1.
// Round-10 null (kv 2-deep +0) falsified block-level MLP as the limiter ->
// cut VALU/edge instead: ea now read from the PERMUTED buffer at the uniform
// loop index -> scalar s_load into SGPRs (frees the vector pipe, kills the
// 18 rotate v_movs -> s_movs, removes the et.x indirection + address chain).
// kv pipeline back to 1-deep (round-9 best). Weights pinned opaque
// (AGPR-resident). No running max (|compat| < ~30; exp safe in fp32).
// ---------------------------------------------------------------------------
__global__ __launch_bounds__(128, 2) void node_attn(
    const float* __restrict__ qbuf, const __half* __restrict__ kv,
    const int* __restrict__ tlist, const int* __restrict__ off,
    const float* __restrict__ eaperm,
    const float* __restrict__ Wq_rpe, const float* __restrict__ bq_rpe,
    const float* __restrict__ Wk_rpe, const float* __restrict__ bk_rpe,
    float* __restrict__ out, int Nn)
{
    int tid = threadIdx.x;
    int n = blockIdx.x;

    // resident RPE weight columns for this thread's qk dim (= tid)
    float wq[INRPE], wk[INRPE];
    #pragma unroll
    for (int j = 0; j < INRPE; j++) {
        wq[j] = Wq_rpe[j * DH + tid];
        wk[j] = Wk_rpe[j * DH + tid];
    }
    #pragma unroll
    for (int j = 0; j < INRPE; j++) {
        asm volatile("" : "+v"(wq[j]), "+v"(wk[j]));
    }

    float qs = qbuf[(size_t)n * DH + tid] + bq_rpe[tid];
    float bkv = bk_rpe[tid];

    int beg = off[n], end = off[n + 1];
    if (beg == end) {
        *(float2*)&out[(size_t)n * DIMX + 2 * tid] = make_float2(0.f, 0.f);
        return;
    }

    float lsum = 0.0f;
    float2 o = make_float2(0.f, 0.f);

    // ---- prologue: stage edge 'beg' (kv + ea); target idx one more ahead ----
    int tC = tlist[beg];
    __half  ktc = kv[(size_t)tC * KVW + tid];
    __half2 vtc = *(const __half2*)&kv[(size_t)tC * KVW + DH + 2 * tid];
    float eac[INRPE];
    {
        const float2* p = (const float2*)(eaperm + (size_t)beg * INRPE);
        #pragma unroll
        for (int j = 0; j < 9; j++) { float2 u = p[j]; eac[2*j] = u.x; eac[2*j+1] = u.y; }
    }
    int tN = tlist[(beg + 1 < end) ? beg + 1 : beg];

    #pragma unroll 1
    for (int i = beg; i < end; i++) {
        // ---- issue next stage (edge i+1): kv gather + uniform ea load ----
        int i2 = (i + 2 < end) ? i + 2 : end - 1;
        int tN2 = tlist[i2];
        __half  ktn = kv[(size_t)tN * KVW + tid];
        __half2 vtn = *(const __half2*)&kv[(size_t)tN * KVW + DH + 2 * tid];
        int i1 = (i + 1 < end) ? i + 1 : end - 1;
        float ean[INRPE];
        {
            const float2* p = (const float2*)(eaperm + (size_t)i1 * INRPE);
            #pragma unroll
            for (int j = 0; j < 9; j++) { float2 u = p[j]; ean[2*j] = u.x; ean[2*j+1] = u.y; }
        }

        // ---- compute edge i (all operands resident; ea from SGPRs) ----
        float qr = 0.f, kr = bkv;
        #pragma unroll
        for (int j = 0; j < INRPE; j++) {
            qr = fmaf(eac[j], wq[j], qr);
            kr = fmaf(eac[j], wk[j], kr);
        }

        float c2 = (qs + qr) * (__half2float(ktc) + kr);
        c2 += __shfl_xor(c2, 1, 64);
        c2 += __shfl_xor(c2, 2, 64);
        c2 += __shfl_xor(c2, 4, 64);

        float ex = __expf(c2);
        float2 vf = __half22float2(vtc);
        lsum += ex;
        o.x = fmaf(ex, vf.x, o.x);
        o.y = fmaf(ex, vf.y, o.y);

        // ---- rotate pipeline (ea rotate is scalar movs if SGPR-resident) ----
        ktc = ktn; vtc = vtn; tN = tN2;
        #pragma unroll
        for (int j = 0; j < INRPE; j++) eac[j] = ean[j];
    }

    float inv = 1.0f / (lsum + 1e-16f);
    *(float2*)&out[(size_t)n * DIMX + 2 * tid] = make_float2(o.x * inv, o.y * inv);
}

// ---------------------------------------------------------------------------
extern "C" void kernel_launch(void* const* d_in, const int* in_sizes, int n_in,
                              void* d_out, int out_size, void* d_ws, size_t ws_size,
                              hipStream_t stream)
{
    const float* x    = (const float*)d_in[0];
    const int*   ei   = (const int*)d_in[1];     // int32! harness converts int64 -> int
    const float* ea   = (const float*)d_in[2];
    const float* Wqkv = (const float*)d_in[3];
    const float* bqkv = (const float*)d_in[4];
    const float* Wk   = (const float*)d_in[5];
    const float* bk   = (const float*)d_in[6];
    const float* Wq   = (const float*)d_in[7];
    const float* bq   = (const float*)d_in[8];

    int Nn = in_sizes[0] / DIMX;
    int E  = in_sizes[1] / 2;
    float* out = (float*)d_out;

    int Mblocks = (Nn + 127) / 128;
    int Mpad    = Mblocks * 128;
    int nchunk  = (Nn + 1023) / 1024;

    // workspace layout:
    //   [ qbuf : Nn*128 f32 ][ kvb : Nn*384 fp16 ]
    //   [ region P: gemm phase = xh/xl (Mpad*256 bf16 each) + wth/wtl
    //               csr  phase = deg/cur/off/tlist/eaperm/psum/pbase (aliased) ]
    size_t qb_bytes = (size_t)Nn * DH * sizeof(float);
    size_t kv_bytes = (size_t)Nn * KVW * sizeof(__half);
    float*  qbuf = (float*)d_ws;
    __half* kvb  = (__half*)((char*)d_ws + qb_bytes);
    char*   P    = (char*)d_ws + qb_bytes + kv_bytes;

    size_t xpart  = (size_t)Mpad * DIMX * sizeof(unsigned short);
    size_t wpart  = (size_t)QKVW * DIMX * sizeof(unsigned short);
    size_t gemm_bytes = 2 * xpart + 2 * wpart;
    size_t csr_bytes  = sizeof(int) * (size_t)(3 * Nn + 2 + 2 * nchunk + 8)
                      + sizeof(int) * (size_t)E
                      + sizeof(float) * (size_t)E * INRPE;
    size_t need = qb_bytes + kv_bytes
                + (gemm_bytes > csr_bytes ? gemm_bytes : csr_bytes);

    // CSR aliases (used strictly after the gemm has consumed xh/xl)
    int*   deg    = (int*)P;
    int*   cur    = deg + Nn;
    int*   off    = cur + Nn;
    int*   tlist  = off + ((Nn + 2) & ~1);          // E ints
    float* eaperm = (float*)(tlist + ((E + 1) & ~1));  // E*18 f32, 8B-aligned
    int*   psum   = (int*)(eaperm + (size_t)E * INRPE);
    int*   pbase  = psum + nchunk;

    if (ws_size >= need) {
        unsigned short* xh  = (unsigned short*)P;
        unsigned short* xl  = xh + (size_t)Mpad * DIMX;
        unsigned short* wth = xl + (size_t)Mpad * DIMX;
        unsigned short* wtl = wth + (size_t)QKVW * DIMX;

        convert_x<<<2048, 256, 0, stream>>>(x, xh, xl, Nn, Mpad);
        convert_w<<<QKVW, 256, 0, stream>>>(Wqkv, wth, wtl);
        // grid (4, Mblocks): col-panels adjacent -> A rows fetched once
        qkv_gemm_mfma<<<dim3(4, Mblocks), 256, 0, stream>>>(xh, xl, wth, wtl,
                                                            bqkv, qbuf, kvb, Nn);
    } else {
        qkv_gemm<<<dim3(Mblocks, QKVW / 128), 256, 0, stream>>>(x, Wqkv, bqkv,
                                                                qbuf, kvb, Nn);
    }

    // CSR build AFTER gemm (deg/cur/... alias the bf16 staging region)
    hipMemsetAsync(deg, 0, sizeof(int) * 2 * (size_t)Nn, stream);
    count_kernel<<<(E + 255) / 256, 256, 0, stream>>>(ei, deg, E);
    scan_sums<<<nchunk, 256, 0, stream>>>(deg, psum, Nn);
    scan_base<<<1, 64, 0, stream>>>(psum, pbase, off, Nn, nchunk);
    scan_final<<<nchunk, 256, 0, stream>>>(deg, pbase, off, Nn);
    scatter_kernel<<<(E + 255) / 256, 256, 0, stream>>>(ei, ea, off, cur,
                                                        tlist, eaperm, E);

    node_attn<<<Nn, 128, 0, stream>>>(qbuf, kvb, tlist, off, eaperm,
                                      Wq, bq, Wk, bk, out, Nn);
}